// Round 1
// baseline (65.177 us; speedup 1.0000x reference)
//
#include <hip/hip_runtime.h>
#include <hip/hip_bf16.h>

typedef __bf16 bf16x8 __attribute__((ext_vector_type(8)));
typedef float  f32x4  __attribute__((ext_vector_type(4)));

#define B_ROWS 8192
#define IN_DIM 256
#define OUT_DIM 32
#define NCLS 50
#define INV_T (1.0f / 0.6f)

// Kernel A: per class c, gamma[i] = sum_o |W[c,o,i]|; alpha_norm[i] = exp((g_i - g_max)/T);
// write W'[c,o,i] = bf16(W[c,o,i] * alpha_norm[i])
__global__ __launch_bounds__(256) void prep_w(const float* __restrict__ w,
                                              __bf16* __restrict__ wb) {
    int c = blockIdx.x;
    int i = threadIdx.x;  // 0..255 == IN index
    const float* wc = w + (size_t)c * OUT_DIM * IN_DIM;
    float g = 0.f;
#pragma unroll
    for (int o = 0; o < OUT_DIM; ++o) g += fabsf(wc[o * IN_DIM + i]);
    // block-wide max over 256 gammas
    float m = g;
#pragma unroll
    for (int s = 1; s < 64; s <<= 1) m = fmaxf(m, __shfl_xor(m, s));
    __shared__ float wm[4];
    if ((threadIdx.x & 63) == 0) wm[threadIdx.x >> 6] = m;
    __syncthreads();
    m = fmaxf(fmaxf(wm[0], wm[1]), fmaxf(wm[2], wm[3]));
    float an = __expf((g - m) * INV_T);
    __bf16* wbc = wb + (size_t)c * OUT_DIM * IN_DIM;
#pragma unroll
    for (int o = 0; o < OUT_DIM; ++o)
        wbc[o * IN_DIM + i] = (__bf16)(wc[o * IN_DIM + i] * an);
}

// Kernel B: x f32 -> bf16, 8 elems/thread, vectorized
__global__ __launch_bounds__(256) void cvt_x(const float* __restrict__ x,
                                             __bf16* __restrict__ xb) {
    int i = (blockIdx.x * 256 + threadIdx.x) * 8;
    float4 v0 = *reinterpret_cast<const float4*>(x + i);
    float4 v1 = *reinterpret_cast<const float4*>(x + i + 4);
    bf16x8 r;
    r[0] = (__bf16)v0.x; r[1] = (__bf16)v0.y; r[2] = (__bf16)v0.z; r[3] = (__bf16)v0.w;
    r[4] = (__bf16)v1.x; r[5] = (__bf16)v1.y; r[6] = (__bf16)v1.z; r[7] = (__bf16)v1.w;
    *reinterpret_cast<bf16x8*>(xb + i) = r;
}

// Kernel C: batched GEMM. out[b, c, o] = sum_i xb[b,i]*wb[c,o,i] + bias[c,o]
// grid = 64 m-tiles * 50 classes; block = 256 threads = 4 waves; wave owns 32(M)x32(N)
__global__ __launch_bounds__(256) void gemm(const __bf16* __restrict__ xb,
                                            const __bf16* __restrict__ wb,
                                            const float* __restrict__ bias,
                                            float* __restrict__ out) {
    int bid = blockIdx.x;
    int mtile = bid & 63;
    int c = bid >> 6;
    int lane = threadIdx.x & 63;
    int wave = threadIdx.x >> 6;
    int m_base = mtile * 128 + wave * 32;
    int l15 = lane & 15;
    int kgrp = (lane >> 4) * 8;  // k-offset of this lane's 8 contiguous bf16

    const __bf16* a0 = xb + (size_t)(m_base + l15) * IN_DIM + kgrp;
    const __bf16* a1 = a0 + 16 * IN_DIM;
    const __bf16* b0 = wb + ((size_t)c * OUT_DIM + l15) * IN_DIM + kgrp;
    const __bf16* b1 = b0 + 16 * IN_DIM;

    f32x4 acc00 = {0.f, 0.f, 0.f, 0.f};
    f32x4 acc01 = {0.f, 0.f, 0.f, 0.f};
    f32x4 acc10 = {0.f, 0.f, 0.f, 0.f};
    f32x4 acc11 = {0.f, 0.f, 0.f, 0.f};

#pragma unroll
    for (int kk = 0; kk < 8; ++kk) {
        int k = kk * 32;
        bf16x8 va0 = *reinterpret_cast<const bf16x8*>(a0 + k);
        bf16x8 va1 = *reinterpret_cast<const bf16x8*>(a1 + k);
        bf16x8 vb0 = *reinterpret_cast<const bf16x8*>(b0 + k);
        bf16x8 vb1 = *reinterpret_cast<const bf16x8*>(b1 + k);
        acc00 = __builtin_amdgcn_mfma_f32_16x16x32_bf16(va0, vb0, acc00, 0, 0, 0);
        acc01 = __builtin_amdgcn_mfma_f32_16x16x32_bf16(va0, vb1, acc01, 0, 0, 0);
        acc10 = __builtin_amdgcn_mfma_f32_16x16x32_bf16(va1, vb0, acc10, 0, 0, 0);
        acc11 = __builtin_amdgcn_mfma_f32_16x16x32_bf16(va1, vb1, acc11, 0, 0, 0);
    }

    float bv0 = bias[c * OUT_DIM + l15];
    float bv1 = bias[c * OUT_DIM + 16 + l15];
    int r0 = m_base + (lane >> 4) * 4;
    size_t ostride = (size_t)NCLS * OUT_DIM;  // 1600
#pragma unroll
    for (int r = 0; r < 4; ++r) {
        out[(size_t)(r0 + r) * ostride + c * OUT_DIM + l15]           = acc00[r] + bv0;
        out[(size_t)(r0 + r) * ostride + c * OUT_DIM + 16 + l15]      = acc01[r] + bv1;
        out[(size_t)(r0 + 16 + r) * ostride + c * OUT_DIM + l15]      = acc10[r] + bv0;
        out[(size_t)(r0 + 16 + r) * ostride + c * OUT_DIM + 16 + l15] = acc11[r] + bv1;
    }
}

extern "C" void kernel_launch(void* const* d_in, const int* in_sizes, int n_in,
                              void* d_out, int out_size, void* d_ws, size_t ws_size,
                              hipStream_t stream) {
    const float* x    = (const float*)d_in[0];
    const float* w    = (const float*)d_in[1];
    const float* bias = (const float*)d_in[2];
    float* out = (float*)d_out;

    __bf16* xb = (__bf16*)d_ws;                       // 8192*256 bf16 = 4 MB
    __bf16* wb = xb + (size_t)B_ROWS * IN_DIM;        // 50*32*256 bf16 = 0.8 MB

    prep_w<<<NCLS, 256, 0, stream>>>(w, wb);
    cvt_x<<<(B_ROWS * IN_DIM) / (256 * 8), 256, 0, stream>>>(x, xb);
    gemm<<<64 * NCLS, 256, 0, stream>>>(xb, wb, bias, out);
}

// Round 2
// 56.298 us; speedup vs baseline: 1.1577x; 1.1577x over previous
//
#include <hip/hip_runtime.h>
#include <hip/hip_bf16.h>

typedef __bf16 bf16x8 __attribute__((ext_vector_type(8)));
typedef float  f32x4  __attribute__((ext_vector_type(4)));

#define B_ROWS 8192
#define IN_DIM 256
#define OUT_DIM 32
#define NCLS 50
#define INV_T (1.0f / 0.6f)

#define CVT_BLOCKS 1024  // 8192*256 / (256 threads * 8 elems)

// Fused prep: blocks [0,1024) convert x f32->bf16; blocks [1024,1074) build
// W'[c,o,i] = bf16(W[c,o,i] * alpha_norm[c,i]),
// alpha_norm[c,i] = exp((gamma[c,i]-max_i gamma)/T), gamma = sum_o |W|.
__global__ __launch_bounds__(256) void prep(const float* __restrict__ x,
                                            const float* __restrict__ w,
                                            __bf16* __restrict__ xb,
                                            __bf16* __restrict__ wb) {
    int bid = blockIdx.x;
    if (bid < CVT_BLOCKS) {
        int i = (bid * 256 + threadIdx.x) * 8;
        float4 v0 = *reinterpret_cast<const float4*>(x + i);
        float4 v1 = *reinterpret_cast<const float4*>(x + i + 4);
        bf16x8 r;
        r[0] = (__bf16)v0.x; r[1] = (__bf16)v0.y; r[2] = (__bf16)v0.z; r[3] = (__bf16)v0.w;
        r[4] = (__bf16)v1.x; r[5] = (__bf16)v1.y; r[6] = (__bf16)v1.z; r[7] = (__bf16)v1.w;
        *reinterpret_cast<bf16x8*>(xb + i) = r;
    } else {
        int c = bid - CVT_BLOCKS;
        int i = threadIdx.x;  // IN index
        const float* wc = w + (size_t)c * OUT_DIM * IN_DIM;
        float g = 0.f;
#pragma unroll
        for (int o = 0; o < OUT_DIM; ++o) g += fabsf(wc[o * IN_DIM + i]);
        float m = g;
#pragma unroll
        for (int s = 1; s < 64; s <<= 1) m = fmaxf(m, __shfl_xor(m, s));
        __shared__ float wm[4];
        if ((threadIdx.x & 63) == 0) wm[threadIdx.x >> 6] = m;
        __syncthreads();
        m = fmaxf(fmaxf(wm[0], wm[1]), fmaxf(wm[2], wm[3]));
        float an = __expf((g - m) * INV_T);
        __bf16* wbc = wb + (size_t)c * OUT_DIM * IN_DIM;
#pragma unroll
        for (int o = 0; o < OUT_DIM; ++o)
            wbc[o * IN_DIM + i] = (__bf16)(wc[o * IN_DIM + i] * an);
    }
}

// Batched GEMM: out[b, c, o] = sum_i xb[b,i]*wb[c,o,i] + bias[c,o]
// grid = 32 m-tiles * 50 classes; block = 256 threads = 4 waves.
// Wave owns M=64 (4 sub-tiles of 16) x N=32. MFMA operands SWAPPED:
// mfma(W_frag, x_frag, acc) -> D col(lane&15)=b row, D row((lane>>4)*4+r)=o.
// => each lane's acc f32x4 is 4 consecutive o -> one dwordx4 store.
__global__ __launch_bounds__(256) void gemm(const __bf16* __restrict__ xb,
                                            const __bf16* __restrict__ wb,
                                            const float* __restrict__ bias,
                                            float* __restrict__ out) {
    int bid = blockIdx.x;
    int mtile = bid & 31;
    int c = bid >> 5;
    int lane = threadIdx.x & 63;
    int wave = threadIdx.x >> 6;
    int m_base = mtile * 256 + wave * 64;
    int l15 = lane & 15;
    int kgrp = (lane >> 4) * 8;  // this lane's 8 contiguous bf16 along K

    const __bf16* a = xb + (size_t)(m_base + l15) * IN_DIM + kgrp;
    const __bf16* b = wb + ((size_t)c * OUT_DIM + l15) * IN_DIM + kgrp;

    f32x4 acc[4][2] = {};

#pragma unroll
    for (int kk = 0; kk < 8; ++kk) {
        int k = kk * 32;
        bf16x8 vb0 = *reinterpret_cast<const bf16x8*>(b + k);
        bf16x8 vb1 = *reinterpret_cast<const bf16x8*>(b + 16 * IN_DIM + k);
#pragma unroll
        for (int m = 0; m < 4; ++m) {
            bf16x8 va = *reinterpret_cast<const bf16x8*>(a + (size_t)m * 16 * IN_DIM + k);
            acc[m][0] = __builtin_amdgcn_mfma_f32_16x16x32_bf16(vb0, va, acc[m][0], 0, 0, 0);
            acc[m][1] = __builtin_amdgcn_mfma_f32_16x16x32_bf16(vb1, va, acc[m][1], 0, 0, 0);
        }
    }

    int obase = (lane >> 4) * 4;
    float4 bv0 = *reinterpret_cast<const float4*>(bias + c * OUT_DIM + obase);
    float4 bv1 = *reinterpret_cast<const float4*>(bias + c * OUT_DIM + 16 + obase);

#pragma unroll
    for (int m = 0; m < 4; ++m) {
        int row = m_base + m * 16 + l15;
        float* p = out + (size_t)row * (NCLS * OUT_DIM) + c * OUT_DIM;
        f32x4 v0 = acc[m][0];
        v0[0] += bv0.x; v0[1] += bv0.y; v0[2] += bv0.z; v0[3] += bv0.w;
        f32x4 v1 = acc[m][1];
        v1[0] += bv1.x; v1[1] += bv1.y; v1[2] += bv1.z; v1[3] += bv1.w;
        *reinterpret_cast<f32x4*>(p + obase) = v0;
        *reinterpret_cast<f32x4*>(p + 16 + obase) = v1;
    }
}

extern "C" void kernel_launch(void* const* d_in, const int* in_sizes, int n_in,
                              void* d_out, int out_size, void* d_ws, size_t ws_size,
                              hipStream_t stream) {
    const float* x    = (const float*)d_in[0];
    const float* w    = (const float*)d_in[1];
    const float* bias = (const float*)d_in[2];
    float* out = (float*)d_out;

    __bf16* xb = (__bf16*)d_ws;                       // 8192*256 bf16 = 4 MB
    __bf16* wb = xb + (size_t)B_ROWS * IN_DIM;        // 50*32*256 bf16 = 0.8 MB

    prep<<<CVT_BLOCKS + NCLS, 256, 0, stream>>>(x, w, xb, wb);
    gemm<<<32 * NCLS, 256, 0, stream>>>(xb, wb, bias, out);
}